// Round 1
// baseline (315.192 us; speedup 1.0000x reference)
//
#include <hip/hip_runtime.h>
#include <stdint.h>

typedef __bf16 bf16_t;
typedef __bf16 bf16x4 __attribute__((ext_vector_type(4)));
typedef __bf16 bf16x8 __attribute__((ext_vector_type(8)));
typedef float  f32x4  __attribute__((ext_vector_type(4)));
typedef short  short4v __attribute__((ext_vector_type(4)));

#define BB   4
#define SS   2048
#define DD   1024
#define HH   16
#define DH   64

#if __has_builtin(__builtin_amdgcn_exp2f)
#define EXP2F(x) __builtin_amdgcn_exp2f(x)
#else
#define EXP2F(x) __expf((x) * 0.6931471805599453f)
#endif

// ---------------------------------------------------------------- helpers
__device__ __forceinline__ void gload_lds16(const void* g, void* l) {
    // dest LDS addr = wave-uniform base + lane*16 (measured m104/m108)
    __builtin_amdgcn_global_load_lds(
        (__attribute__((address_space(1))) void*)(uintptr_t)g,
        (__attribute__((address_space(3))) void*)(uint32_t)(uintptr_t)l,
        16, 0, 0);
}

// K=16 bf16 MFMA: A-fragment layout (row=l&15, cols=(l>>4)*4+0..3) exactly
// matches the 16x16 D-fragment of the QK^T MFMA, so P never leaves registers.
__device__ __forceinline__ f32x4 mfma16(short4v a, short4v b, f32x4 c) {
#if __has_builtin(__builtin_amdgcn_mfma_f32_16x16x16bf16_1k)
    return __builtin_amdgcn_mfma_f32_16x16x16bf16_1k(a, b, c, 0, 0, 0);
#else
    asm("v_mfma_f32_16x16x16_bf16 %0, %1, %2, %0" : "+v"(c) : "v"(a), "v"(b));
    return c;
#endif
}

// ---------------------------------------------------------------- fused prep
// one launch: X fp32->bf16 (8192 blocks), 4 weights fp32->bf16 (4096),
// rope cos/sin table (4096), bias pack (12). grid = 16396.
__global__ __launch_bounds__(256) void prep_kernel(
        const float* __restrict__ queries,
        const float* __restrict__ Wq, const float* __restrict__ Wk,
        const float* __restrict__ Wv, const float* __restrict__ Wo,
        const float* __restrict__ bq, const float* __restrict__ bk,
        const float* __restrict__ bv,
        bf16_t* __restrict__ Xb, bf16_t* __restrict__ Wqkv,
        bf16_t* __restrict__ Wob, float* __restrict__ bqkv,
        float2* __restrict__ tab)
{
    const int bid = blockIdx.x, t = threadIdx.x;
    if (bid < 8192) {                       // X convert: 2097152 float4
        const int i = bid * 256 + t;
        float4 v = ((const float4*)queries)[i];
        bf16x4 o;
        o.x = (bf16_t)v.x; o.y = (bf16_t)v.y; o.z = (bf16_t)v.z; o.w = (bf16_t)v.w;
        ((bf16x4*)Xb)[i] = o;
    } else if (bid < 12288) {               // weights: 1048576 float4
        const int i = (bid - 8192) * 256 + t;
        const int which = i >> 18, p = i & 262143;
        const float* src = (which == 0) ? Wq : (which == 1) ? Wk : (which == 2) ? Wv : Wo;
        bf16_t* dst = (which < 3) ? (Wqkv + (long)which * 1048576) : Wob;
        float4 v = ((const float4*)src)[p];
        bf16x4 o;
        o.x = (bf16_t)v.x; o.y = (bf16_t)v.y; o.z = (bf16_t)v.z; o.w = (bf16_t)v.w;
        ((bf16x4*)dst)[p] = o;
    } else if (bid < 16384) {               // rope table: 2048*512 entries
        const int i = (bid - 12288) * 256 + t;
        const int s = i >> 9, pr = i & 511;
        float inv = powf(10000.0f, -(float)(2 * pr) * (1.0f / 1024.0f));
        float c, sn;
        sincosf((float)s * inv, &sn, &c);
        tab[i] = make_float2(c, sn);
    } else {                                // bias pack: 3072
        const int i = (bid - 16384) * 256 + t;
        if (i < 3072)
            bqkv[i] = (i < 1024) ? bq[i] : ((i < 2048) ? bk[i - 1024] : bv[i - 2048]);
    }
}

// ---------------------------------------------------------------- fused QKV GEMM + bias + RoPE + V-transpose
// C = X @ Wqkv^T + bqkv. Q/K cols -> rope -> Qb/Kb (bh, s, d); V cols ->
// written TRANSPOSED directly to Vt (bh, d, s).
__global__ __launch_bounds__(256, 3) void gemm_qkv_rope(
        const bf16_t* __restrict__ A, const bf16_t* __restrict__ Bm,
        const float* __restrict__ bias, const float2* __restrict__ tab,
        bf16_t* __restrict__ Qb, bf16_t* __restrict__ Kb, bf16_t* __restrict__ Vt)
{
    __shared__ __attribute__((aligned(16))) bf16_t As[128 * 32];
    __shared__ __attribute__((aligned(16))) bf16_t Bs[128 * 32];
    const int t = threadIdx.x;
    const int lane = t & 63, w = t >> 6;
    const int wm = w >> 1, wn = w & 1;
    const int l15 = lane & 15, l4 = lane >> 4;
    const int xg = l15 & 3;                  // read-side swizzle (= row&3)
    const long rowA0 = (long)blockIdx.x * 128;
    const long rowB0 = (long)blockIdx.y * 128;
    const int K = 1024;

    const f32x4 vz = {0.f, 0.f, 0.f, 0.f};
    f32x4 acc[4][4];
#pragma unroll
    for (int i = 0; i < 4; ++i)
#pragma unroll
        for (int j = 0; j < 4; ++j) acc[i][j] = vz;

    for (int kk = 0; kk < K; kk += 32) {
        __syncthreads();
#pragma unroll
        for (int i = 0; i < 2; ++i) {
            const int cb = i * 256 + w * 64;
            const int c  = cb + lane;
            const int r  = c >> 2;
            const int ko = ((c & 3) ^ (r & 3)) << 3;   // swizzled src chunk
            gload_lds16(A  + (rowA0 + r) * K + kk + ko, As + cb * 8);
            gload_lds16(Bm + (rowB0 + r) * K + kk + ko, Bs + cb * 8);
        }
        __syncthreads();
        bf16x8 af[4], bfr[4];
#pragma unroll
        for (int i = 0; i < 4; ++i)
            af[i] = *(const bf16x8*)(As + (wm * 64 + i * 16 + l15) * 32 + ((l4 ^ xg) * 8));
#pragma unroll
        for (int j = 0; j < 4; ++j)
            bfr[j] = *(const bf16x8*)(Bs + (wn * 64 + j * 16 + l15) * 32 + ((l4 ^ xg) * 8));
#pragma unroll
        for (int i = 0; i < 4; ++i)
#pragma unroll
            for (int j = 0; j < 4; ++j)
                acc[i][j] = __builtin_amdgcn_mfma_f32_16x16x32_bf16(af[i], bfr[j], acc[i][j], 0, 0, 0);
    }

    const long crow0 = rowA0 + wm * 64;
    const int  ccol0 = (int)rowB0 + wn * 64;     // global col in [0,3072), multiple of 64
    const int  part  = blockIdx.y >> 3;          // 0=Q, 1=K, 2=V
    const int  b     = (int)(crow0 >> 11);
    const int  s0    = (int)(crow0 & 2047);      // 64 rows stay in one batch

    if (part == 2) {
        const int h = (ccol0 - 2048) >> 6;       // wave-constant head
#pragma unroll
        for (int j = 0; j < 4; ++j) {
            const int d = j * 16 + l15;
            const float bb = bias[ccol0 + j * 16 + l15];
            bf16_t* dstc = Vt + ((long)(b * HH + h) * DH + d) * SS + s0;
#pragma unroll
            for (int i = 0; i < 4; ++i) {
                bf16x4 pk;
                pk.x = (bf16_t)(acc[i][j][0] + bb);
                pk.y = (bf16_t)(acc[i][j][1] + bb);
                pk.z = (bf16_t)(acc[i][j][2] + bb);
                pk.w = (bf16_t)(acc[i][j][3] + bb);
                *(bf16x4*)(dstc + i * 16 + l4 * 4) = pk;
            }
        }
    } else {
        bf16_t* dst0 = part ? Kb : Qb;
        const int h = (ccol0 & 1023) >> 6;       // this wave's 64-col strip = one head
        const int even = !(l15 & 1);
#pragma unroll
        for (int i = 0; i < 4; ++i) {
#pragma unroll
            for (int j = 0; j < 4; ++j) {
                const int col = ccol0 + j * 16 + l15;
                const float bb = bias[col];
                const int dd = j * 16 + l15;
                const float2* trow = tab + (col >> 1 & 511);
#pragma unroll
                for (int r = 0; r < 4; ++r) {
                    const int s = s0 + i * 16 + l4 * 4 + r;
                    const float val = acc[i][j][r] + bb;
                    const float par = __shfl_xor(val, 1);
                    const float2 cs = trow[s * 512];
                    const float out = even ? (val * cs.x - par * cs.y)
                                           : fmaf(val, cs.x, par * cs.y);
                    // pair-store: even lane writes {out_even, out_odd} as b32
                    const float op = __shfl_xor(out, 1);
                    if (even) {
                        union { bf16_t hh[2]; unsigned int u; } cv;
                        cv.hh[0] = (bf16_t)out; cv.hh[1] = (bf16_t)op;
                        *(unsigned int*)(dst0 + ((long)((b * HH + h) * SS + s)) * DH + dd) = cv.u;
                    }
                }
            }
        }
    }
}

// ---------------------------------------------------------------- NT GEMM (output projection)
template <int OUT_BF16>
__global__ __launch_bounds__(256, 3) void gemm_bt(
        const bf16_t* __restrict__ A, const bf16_t* __restrict__ Bm,
        const float* __restrict__ bias, void* __restrict__ Cout,
        int M, int N, int K)
{
    __shared__ __attribute__((aligned(16))) bf16_t As[128 * 32];
    __shared__ __attribute__((aligned(16))) bf16_t Bs[128 * 32];
    const int t = threadIdx.x;
    const int lane = t & 63, w = t >> 6;
    const int wm = w >> 1, wn = w & 1;
    const int l15 = lane & 15, l4 = lane >> 4;
    const int xg = l15 & 3;
    const long rowA0 = (long)blockIdx.x * 128;
    const long rowB0 = (long)blockIdx.y * 128;

    const f32x4 vz = {0.f, 0.f, 0.f, 0.f};
    f32x4 acc[4][4];
#pragma unroll
    for (int i = 0; i < 4; ++i)
#pragma unroll
        for (int j = 0; j < 4; ++j) acc[i][j] = vz;

    for (int kk = 0; kk < K; kk += 32) {
        __syncthreads();
#pragma unroll
        for (int i = 0; i < 2; ++i) {
            const int cb = i * 256 + w * 64;
            const int c  = cb + lane;
            const int r  = c >> 2;
            const int ko = ((c & 3) ^ (r & 3)) << 3;   // swizzled src chunk
            gload_lds16(A  + (rowA0 + r) * K + kk + ko, As + cb * 8);
            gload_lds16(Bm + (rowB0 + r) * K + kk + ko, Bs + cb * 8);
        }
        __syncthreads();
        bf16x8 af[4], bfr[4];
#pragma unroll
        for (int i = 0; i < 4; ++i)
            af[i] = *(const bf16x8*)(As + (wm * 64 + i * 16 + l15) * 32 + ((l4 ^ xg) * 8));
#pragma unroll
        for (int j = 0; j < 4; ++j)
            bfr[j] = *(const bf16x8*)(Bs + (wn * 64 + j * 16 + l15) * 32 + ((l4 ^ xg) * 8));
#pragma unroll
        for (int i = 0; i < 4; ++i)
#pragma unroll
            for (int j = 0; j < 4; ++j)
                acc[i][j] = __builtin_amdgcn_mfma_f32_16x16x32_bf16(af[i], bfr[j], acc[i][j], 0, 0, 0);
    }

    const long crow0 = rowA0 + wm * 64;
    const int  ccol0 = (int)rowB0 + wn * 64;
#pragma unroll
    for (int i = 0; i < 4; ++i) {
#pragma unroll
        for (int j = 0; j < 4; ++j) {
            const int col = ccol0 + j * 16 + l15;
            const float bb = bias[col];
#pragma unroll
            for (int r = 0; r < 4; ++r) {
                const long row = crow0 + i * 16 + l4 * 4 + r;
                const float v = acc[i][j][r] + bb;
                if (OUT_BF16) ((bf16_t*)Cout)[row * N + col] = (bf16_t)v;
                else          ((float*)Cout)[row * N + col]  = v;
            }
        }
    }
}

// ---------------------------------------------------------------- flash attention
// R9: latency-bound fix (MfmaUtil 30 / VALUBusy 41 / Occ 33 @ 4 blocks/CU):
//  - PV uses v_mfma_f32_16x16x16_bf16: its A-fragment (row=l15, k=l4*4+r) is
//    IDENTICAL to the QK^T D-fragment (q=l15, key=l4*4+r), so P stays in
//    registers. Ps buffer (18.4 KB + its pack/store/reload + conflicts) gone.
//  - LDS 34816 -> 16384 B; q-tile 128 -> 64 rows (1 strip/wave); grid
//    1024 -> 2048 blocks => 8 blocks/CU (launch_bounds(256,8)). More
//    independent blocks = the cross-block overlap that beat dbuf in R7.
//  - grid (bh=64, qt=32): linear id % 8 == bh % 8 pins each bh's K/V to one
//    XCD L2; the 2x staging re-reads stay L2-local, HBM K/V ~1 copy/XCD.
//  - V fragments: 16x ds_read_b64 from the swizzled [d][key] Vs (source chunk
//    cs = kb*2+(l4>>1), sub (l4&1)*4 elems; slot = cs ^ (row&7)). ~4-way.
__global__ __launch_bounds__(256, 8) void attn_kernel(const bf16_t* __restrict__ Qb,
                                                      const bf16_t* __restrict__ Kb,
                                                      const bf16_t* __restrict__ Vt,
                                                      bf16_t* __restrict__ Ob)
{
    __shared__ __attribute__((aligned(16))) bf16_t Ks[64 * 64];   // [key][d], swizzled
    __shared__ __attribute__((aligned(16))) bf16_t Vs[64 * 64];   // [d][key], swizzled
    const int t = threadIdx.x, lane = t & 63, w = t >> 6;
    const int l15 = lane & 15, l4 = lane >> 4;
    const int xr = l15 & 7;               // read-side swizzle pattern (= row&7)
    const int bh = blockIdx.x, qt = blockIdx.y;
    const bf16_t* Qbh = Qb + (long)bh * SS * DH;
    const bf16_t* Kbh = Kb + (long)bh * SS * DH;
    const bf16_t* Vbh = Vt + (long)bh * DH * SS;

    const int qbase = qt * 64 + w * 16;   // this wave's 16 q rows
    bf16x8 qf[2];
    {
        const long qrow = qbase + l15;
        qf[0] = *(const bf16x8*)(Qbh + qrow * DH + l4 * 8);
        qf[1] = *(const bf16x8*)(Qbh + qrow * DH + 32 + l4 * 8);
    }

    const f32x4 vz = {0.f, 0.f, 0.f, 0.f};
    f32x4 oacc[4];
#pragma unroll
    for (int j = 0; j < 4; ++j) oacc[j] = vz;
    float l_sum = 0.f;

    int srow[2], scc[2];
#pragma unroll
    for (int i = 0; i < 2; ++i) {
        const int L = i * 256 + w * 64 + lane;
        srow[i] = L >> 3;
        scc[i]  = (L & 7) ^ (srow[i] & 7);
    }

    const float SC = 0.125f * 1.4426950408889634f;
    const float BI = -8.0f  * 1.4426950408889634f;

    for (int kt = 0; kt < SS / 64; ++kt) {
        __syncthreads();
        const bf16_t* Ksrc = Kbh + (long)kt * 64 * DH;
#pragma unroll
        for (int i = 0; i < 2; ++i) {
            const int cb = i * 256 + w * 64;
            gload_lds16(Ksrc + srow[i] * 64 + scc[i] * 8, Ks + cb * 8);
            gload_lds16(Vbh + (long)srow[i] * SS + kt * 64 + scc[i] * 8, Vs + cb * 8);
        }
        __syncthreads();

        // S^T = K Q^T : sacc[j] holds q=l15 (col), keys j*16 + l4*4 + r (row)
        f32x4 sacc[4];
#pragma unroll
        for (int j = 0; j < 4; ++j) sacc[j] = vz;
#pragma unroll
        for (int j = 0; j < 4; ++j) {
            const int rk = (j * 16 + l15) * 64;
            const bf16x8 kf0 = *(const bf16x8*)(Ks + rk + ((l4 ^ xr) * 8));
            const bf16x8 kf1 = *(const bf16x8*)(Ks + rk + (((4 + l4) ^ xr) * 8));
            sacc[j] = __builtin_amdgcn_mfma_f32_16x16x32_bf16(kf0, qf[0], sacc[j], 0, 0, 0);
            sacc[j] = __builtin_amdgcn_mfma_f32_16x16x32_bf16(kf1, qf[1], sacc[j], 0, 0, 0);
        }

        // p = exp2(s*SC + BI), kept in registers as K=16 A-fragments
        short4v pf[4];
#pragma unroll
        for (int j = 0; j < 4; ++j) {
            const float p0 = EXP2F(fmaf(sacc[j][0], SC, BI));
            const float p1 = EXP2F(fmaf(sacc[j][1], SC, BI));
            const float p2 = EXP2F(fmaf(sacc[j][2], SC, BI));
            const float p3 = EXP2F(fmaf(sacc[j][3], SC, BI));
            l_sum += (p0 + p1) + (p2 + p3);
            union { bf16x4 h; short4v s; } cv;
            cv.h.x = (bf16_t)p0; cv.h.y = (bf16_t)p1;
            cv.h.z = (bf16_t)p2; cv.h.w = (bf16_t)p3;
            pf[j] = cv.s;
        }

        // O += P V : dj = d-block, kb = key quad block (K=16 per MFMA)
#pragma unroll
        for (int dj = 0; dj < 4; ++dj) {
            const bf16_t* vb = Vs + (dj * 16 + l15) * 64 + (l4 & 1) * 4;
#pragma unroll
            for (int kb = 0; kb < 4; ++kb) {
                const int slot = (kb * 2 + (l4 >> 1)) ^ xr;
                const short4v vfr = *(const short4v*)(vb + slot * 8);
                oacc[dj] = mfma16(pf[kb], vfr, oacc[dj]);
            }
        }
    }

    const int b = bh >> 4, h = bh & 15;
    float lt = l_sum;
    lt += __shfl_xor(lt, 16);
    lt += __shfl_xor(lt, 32);
    const float inv = 1.0f / lt;
    float invr[4];
#pragma unroll
    for (int r = 0; r < 4; ++r)
        invr[r] = __shfl(inv, l4 * 4 + r);   // lane l4*4+r holds inv for q'=l4*4+r
#pragma unroll
    for (int j = 0; j < 4; ++j) {
#pragma unroll
        for (int r = 0; r < 4; ++r) {
            const int row = qbase + l4 * 4 + r;
            const float v = oacc[j][r] * invr[r];
            Ob[((long)(b * SS + row)) * DD + h * DH + j * 16 + l15] = (bf16_t)v;
        }
    }
}

// ---------------------------------------------------------------- launch
extern "C" void kernel_launch(void* const* d_in, const int* in_sizes, int n_in,
                              void* d_out, int out_size, void* d_ws, size_t ws_size,
                              hipStream_t stream)
{
    const float* queries = (const float*)d_in[0];
    const float* Wq = (const float*)d_in[1];
    const float* bq = (const float*)d_in[2];
    const float* Wk = (const float*)d_in[3];
    const float* bk = (const float*)d_in[4];
    const float* Wv = (const float*)d_in[5];
    const float* bv = (const float*)d_in[6];
    const float* Wo = (const float*)d_in[7];
    const float* bo = (const float*)d_in[8];

    char* ws = (char*)d_ws;
    size_t off = 0;
    auto alloc = [&](size_t bytes) { size_t o = off; off += (bytes + 255) & ~(size_t)255; return o; };
    bf16_t* Xb   = (bf16_t*)(ws + alloc(8192u * 1024u * 2u));       // 16 MB
    bf16_t* Wqkv = (bf16_t*)(ws + alloc(3072u * 1024u * 2u));       // 6 MB
    bf16_t* Wob  = (bf16_t*)(ws + alloc(1024u * 1024u * 2u));       // 2 MB
    float*  bqkv = (float*) (ws + alloc(3072u * 4u));
    float2* tab  = (float2*)(ws + alloc(2048u * 512u * 8u));        // 8 MB
    bf16_t* Qb   = (bf16_t*)(ws + alloc(64u * 2048u * 64u * 2u));   // 16 MB
    bf16_t* Kb   = (bf16_t*)(ws + alloc(64u * 2048u * 64u * 2u));   // 16 MB
    bf16_t* Vt   = (bf16_t*)(ws + alloc(64u * 64u * 2048u * 2u));   // 16 MB
    bf16_t* Ob   = Xb;  // alias: Xb is dead after GEMM1

    prep_kernel<<<16396, 256, 0, stream>>>(queries, Wq, Wk, Wv, Wo, bq, bk, bv,
                                           Xb, Wqkv, Wob, bqkv, tab);

    gemm_qkv_rope<<<dim3(64, 24), 256, 0, stream>>>(Xb, Wqkv, bqkv, tab, Qb, Kb, Vt);
    attn_kernel<<<dim3(64, 32), 256, 0, stream>>>(Qb, Kb, Vt, Ob);
    gemm_bt<0><<<dim3(64, 8), 256, 0, stream>>>(Ob, Wob, bo, d_out, 8192, 1024, 1024);
}

// Round 2
// 304.427 us; speedup vs baseline: 1.0354x; 1.0354x over previous
//
#include <hip/hip_runtime.h>
#include <stdint.h>

typedef __bf16 bf16_t;
typedef __bf16 bf16x4 __attribute__((ext_vector_type(4)));
typedef __bf16 bf16x8 __attribute__((ext_vector_type(8)));
typedef float  f32x4  __attribute__((ext_vector_type(4)));
typedef short  short4v __attribute__((ext_vector_type(4)));

#define BB   4
#define SS   2048
#define DD   1024
#define HH   16
#define DH   64

#if __has_builtin(__builtin_amdgcn_exp2f)
#define EXP2F(x) __builtin_amdgcn_exp2f(x)
#else
#define EXP2F(x) __expf((x) * 0.6931471805599453f)
#endif

// ---------------------------------------------------------------- helpers
__device__ __forceinline__ void gload_lds16(const void* g, void* l) {
    // dest LDS addr = wave-uniform base + lane*16 (measured m104/m108)
    __builtin_amdgcn_global_load_lds(
        (__attribute__((address_space(1))) void*)(uintptr_t)g,
        (__attribute__((address_space(3))) void*)(uint32_t)(uintptr_t)l,
        16, 0, 0);
}

// K=16 bf16 MFMA: A-fragment layout (row=l&15, cols=(l>>4)*4+0..3) exactly
// matches the 16x16 D-fragment of the QK^T MFMA, so P never leaves registers.
__device__ __forceinline__ f32x4 mfma16(short4v a, short4v b, f32x4 c) {
#if __has_builtin(__builtin_amdgcn_mfma_f32_16x16x16bf16_1k)
    return __builtin_amdgcn_mfma_f32_16x16x16bf16_1k(a, b, c, 0, 0, 0);
#else
    asm("v_mfma_f32_16x16x16_bf16 %0, %1, %2, %0" : "+v"(c) : "v"(a), "v"(b));
    return c;
#endif
}

// ---------------------------------------------------------------- fused prep
// one launch: X fp32->bf16 (8192 blocks), 4 weights fp32->bf16 (4096),
// rope cos/sin table (4096), bias pack (12). grid = 16396.
__global__ __launch_bounds__(256) void prep_kernel(
        const float* __restrict__ queries,
        const float* __restrict__ Wq, const float* __restrict__ Wk,
        const float* __restrict__ Wv, const float* __restrict__ Wo,
        const float* __restrict__ bq, const float* __restrict__ bk,
        const float* __restrict__ bv,
        bf16_t* __restrict__ Xb, bf16_t* __restrict__ Wqkv,
        bf16_t* __restrict__ Wob, float* __restrict__ bqkv,
        float2* __restrict__ tab)
{
    const int bid = blockIdx.x, t = threadIdx.x;
    if (bid < 8192) {                       // X convert: 2097152 float4
        const int i = bid * 256 + t;
        float4 v = ((const float4*)queries)[i];
        bf16x4 o;
        o.x = (bf16_t)v.x; o.y = (bf16_t)v.y; o.z = (bf16_t)v.z; o.w = (bf16_t)v.w;
        ((bf16x4*)Xb)[i] = o;
    } else if (bid < 12288) {               // weights: 1048576 float4
        const int i = (bid - 8192) * 256 + t;
        const int which = i >> 18, p = i & 262143;
        const float* src = (which == 0) ? Wq : (which == 1) ? Wk : (which == 2) ? Wv : Wo;
        bf16_t* dst = (which < 3) ? (Wqkv + (long)which * 1048576) : Wob;
        float4 v = ((const float4*)src)[p];
        bf16x4 o;
        o.x = (bf16_t)v.x; o.y = (bf16_t)v.y; o.z = (bf16_t)v.z; o.w = (bf16_t)v.w;
        ((bf16x4*)dst)[p] = o;
    } else if (bid < 16384) {               // rope table: 2048*512 entries
        const int i = (bid - 12288) * 256 + t;
        const int s = i >> 9, pr = i & 511;
        float inv = powf(10000.0f, -(float)(2 * pr) * (1.0f / 1024.0f));
        float c, sn;
        sincosf((float)s * inv, &sn, &c);
        tab[i] = make_float2(c, sn);
    } else {                                // bias pack: 3072
        const int i = (bid - 16384) * 256 + t;
        if (i < 3072)
            bqkv[i] = (i < 1024) ? bq[i] : ((i < 2048) ? bk[i - 1024] : bv[i - 2048]);
    }
}

// ---------------------------------------------------------------- fused QKV GEMM + bias + RoPE + V-transpose
// C = X @ Wqkv^T + bqkv. Q/K cols -> rope -> Qb/Kb (bh, s, d); V cols ->
// written TRANSPOSED directly to Vt (bh, d, s).
__global__ __launch_bounds__(256, 3) void gemm_qkv_rope(
        const bf16_t* __restrict__ A, const bf16_t* __restrict__ Bm,
        const float* __restrict__ bias, const float2* __restrict__ tab,
        bf16_t* __restrict__ Qb, bf16_t* __restrict__ Kb, bf16_t* __restrict__ Vt)
{
    __shared__ __attribute__((aligned(16))) bf16_t As[128 * 32];
    __shared__ __attribute__((aligned(16))) bf16_t Bs[128 * 32];
    const int t = threadIdx.x;
    const int lane = t & 63, w = t >> 6;
    const int wm = w >> 1, wn = w & 1;
    const int l15 = lane & 15, l4 = lane >> 4;
    const int xg = l15 & 3;                  // read-side swizzle (= row&3)
    const long rowA0 = (long)blockIdx.x * 128;
    const long rowB0 = (long)blockIdx.y * 128;
    const int K = 1024;

    const f32x4 vz = {0.f, 0.f, 0.f, 0.f};
    f32x4 acc[4][4];
#pragma unroll
    for (int i = 0; i < 4; ++i)
#pragma unroll
        for (int j = 0; j < 4; ++j) acc[i][j] = vz;

    for (int kk = 0; kk < K; kk += 32) {
        __syncthreads();
#pragma unroll
        for (int i = 0; i < 2; ++i) {
            const int cb = i * 256 + w * 64;
            const int c  = cb + lane;
            const int r  = c >> 2;
            const int ko = ((c & 3) ^ (r & 3)) << 3;   // swizzled src chunk
            gload_lds16(A  + (rowA0 + r) * K + kk + ko, As + cb * 8);
            gload_lds16(Bm + (rowB0 + r) * K + kk + ko, Bs + cb * 8);
        }
        __syncthreads();
        bf16x8 af[4], bfr[4];
#pragma unroll
        for (int i = 0; i < 4; ++i)
            af[i] = *(const bf16x8*)(As + (wm * 64 + i * 16 + l15) * 32 + ((l4 ^ xg) * 8));
#pragma unroll
        for (int j = 0; j < 4; ++j)
            bfr[j] = *(const bf16x8*)(Bs + (wn * 64 + j * 16 + l15) * 32 + ((l4 ^ xg) * 8));
#pragma unroll
        for (int i = 0; i < 4; ++i)
#pragma unroll
            for (int j = 0; j < 4; ++j)
                acc[i][j] = __builtin_amdgcn_mfma_f32_16x16x32_bf16(af[i], bfr[j], acc[i][j], 0, 0, 0);
    }

    const long crow0 = rowA0 + wm * 64;
    const int  ccol0 = (int)rowB0 + wn * 64;     // global col in [0,3072), multiple of 64
    const int  part  = blockIdx.y >> 3;          // 0=Q, 1=K, 2=V
    const int  b     = (int)(crow0 >> 11);
    const int  s0    = (int)(crow0 & 2047);      // 64 rows stay in one batch

    if (part == 2) {
        const int h = (ccol0 - 2048) >> 6;       // wave-constant head
#pragma unroll
        for (int j = 0; j < 4; ++j) {
            const int d = j * 16 + l15;
            const float bb = bias[ccol0 + j * 16 + l15];
            bf16_t* dstc = Vt + ((long)(b * HH + h) * DH + d) * SS + s0;
#pragma unroll
            for (int i = 0; i < 4; ++i) {
                bf16x4 pk;
                pk.x = (bf16_t)(acc[i][j][0] + bb);
                pk.y = (bf16_t)(acc[i][j][1] + bb);
                pk.z = (bf16_t)(acc[i][j][2] + bb);
                pk.w = (bf16_t)(acc[i][j][3] + bb);
                *(bf16x4*)(dstc + i * 16 + l4 * 4) = pk;
            }
        }
    } else {
        bf16_t* dst0 = part ? Kb : Qb;
        const int h = (ccol0 & 1023) >> 6;       // this wave's 64-col strip = one head
        const int even = !(l15 & 1);
#pragma unroll
        for (int i = 0; i < 4; ++i) {
#pragma unroll
            for (int j = 0; j < 4; ++j) {
                const int col = ccol0 + j * 16 + l15;
                const float bb = bias[col];
                const int dd = j * 16 + l15;
                const float2* trow = tab + (col >> 1 & 511);
#pragma unroll
                for (int r = 0; r < 4; ++r) {
                    const int s = s0 + i * 16 + l4 * 4 + r;
                    const float val = acc[i][j][r] + bb;
                    const float par = __shfl_xor(val, 1);
                    const float2 cs = trow[s * 512];
                    const float out = even ? (val * cs.x - par * cs.y)
                                           : fmaf(val, cs.x, par * cs.y);
                    // pair-store: even lane writes {out_even, out_odd} as b32
                    const float op = __shfl_xor(out, 1);
                    if (even) {
                        union { bf16_t hh[2]; unsigned int u; } cv;
                        cv.hh[0] = (bf16_t)out; cv.hh[1] = (bf16_t)op;
                        *(unsigned int*)(dst0 + ((long)((b * HH + h) * SS + s)) * DH + dd) = cv.u;
                    }
                }
            }
        }
    }
}

// ---------------------------------------------------------------- NT GEMM (output projection)
template <int OUT_BF16>
__global__ __launch_bounds__(256, 3) void gemm_bt(
        const bf16_t* __restrict__ A, const bf16_t* __restrict__ Bm,
        const float* __restrict__ bias, void* __restrict__ Cout,
        int M, int N, int K)
{
    __shared__ __attribute__((aligned(16))) bf16_t As[128 * 32];
    __shared__ __attribute__((aligned(16))) bf16_t Bs[128 * 32];
    const int t = threadIdx.x;
    const int lane = t & 63, w = t >> 6;
    const int wm = w >> 1, wn = w & 1;
    const int l15 = lane & 15, l4 = lane >> 4;
    const int xg = l15 & 3;
    const long rowA0 = (long)blockIdx.x * 128;
    const long rowB0 = (long)blockIdx.y * 128;

    const f32x4 vz = {0.f, 0.f, 0.f, 0.f};
    f32x4 acc[4][4];
#pragma unroll
    for (int i = 0; i < 4; ++i)
#pragma unroll
        for (int j = 0; j < 4; ++j) acc[i][j] = vz;

    for (int kk = 0; kk < K; kk += 32) {
        __syncthreads();
#pragma unroll
        for (int i = 0; i < 2; ++i) {
            const int cb = i * 256 + w * 64;
            const int c  = cb + lane;
            const int r  = c >> 2;
            const int ko = ((c & 3) ^ (r & 3)) << 3;   // swizzled src chunk
            gload_lds16(A  + (rowA0 + r) * K + kk + ko, As + cb * 8);
            gload_lds16(Bm + (rowB0 + r) * K + kk + ko, Bs + cb * 8);
        }
        __syncthreads();
        bf16x8 af[4], bfr[4];
#pragma unroll
        for (int i = 0; i < 4; ++i)
            af[i] = *(const bf16x8*)(As + (wm * 64 + i * 16 + l15) * 32 + ((l4 ^ xg) * 8));
#pragma unroll
        for (int j = 0; j < 4; ++j)
            bfr[j] = *(const bf16x8*)(Bs + (wn * 64 + j * 16 + l15) * 32 + ((l4 ^ xg) * 8));
#pragma unroll
        for (int i = 0; i < 4; ++i)
#pragma unroll
            for (int j = 0; j < 4; ++j)
                acc[i][j] = __builtin_amdgcn_mfma_f32_16x16x32_bf16(af[i], bfr[j], acc[i][j], 0, 0, 0);
    }

    const long crow0 = rowA0 + wm * 64;
    const int  ccol0 = (int)rowB0 + wn * 64;
#pragma unroll
    for (int i = 0; i < 4; ++i) {
#pragma unroll
        for (int j = 0; j < 4; ++j) {
            const int col = ccol0 + j * 16 + l15;
            const float bb = bias[col];
#pragma unroll
            for (int r = 0; r < 4; ++r) {
                const long row = crow0 + i * 16 + l4 * 4 + r;
                const float v = acc[i][j][r] + bb;
                if (OUT_BF16) ((bf16_t*)Cout)[row * N + col] = (bf16_t)v;
                else          ((float*)Cout)[row * N + col]  = v;
            }
        }
    }
}

// ---------------------------------------------------------------- flash attention
// R10 = R8's 128-row q-tile (2 strips/wave: all per-kt shared costs — staging,
// K-frag reads, barriers — amortize over 2x output; R9's 64-row tile doubled
// them per output and LOST 98.5->109.4 despite 2x occupancy)
//   + R9's in-register P (PV via v_mfma_f32_16x16x16_bf16 whose A-fragment ==
//     QK^T D-fragment; Ps buffer + pack/store/reload + its conflicts deleted)
//   + R9's bh-major grid (XCD pinning cut FETCH 139->30 MB)
//   + K/V double-buffer w/ counted vmcnt: LDS is 16 KB without Ps, so dbuf
//     (32 KB) no longer costs a block/CU (R7's dbuf tax is now zero; grid
//     limits us to 4 blocks/CU regardless). Loop = stage(next) ->
//     s_waitcnt vmcnt(4) -> s_barrier -> compute(cur) -> s_barrier.
//     sched_barrier(0) pins around asm waits (rule #18); explicit vmcnt(0)
//     drain after qf loads keeps the compiler's vmcnt model exact so it
//     doesn't insert a draining wait in the loop.
__global__ __launch_bounds__(256, 4) void attn_kernel(const bf16_t* __restrict__ Qb,
                                                      const bf16_t* __restrict__ Kb,
                                                      const bf16_t* __restrict__ Vt,
                                                      bf16_t* __restrict__ Ob)
{
    __shared__ __attribute__((aligned(16))) bf16_t Ks[2 * 64 * 64];  // [buf][key][d], swizzled
    __shared__ __attribute__((aligned(16))) bf16_t Vs[2 * 64 * 64];  // [buf][d][key], swizzled
    const int t = threadIdx.x, lane = t & 63, w = t >> 6;
    const int l15 = lane & 15, l4 = lane >> 4;
    const int xr = l15 & 7;               // read-side swizzle pattern (= row&7)
    const int bh = blockIdx.x, qt = blockIdx.y;
    const bf16_t* Qbh = Qb + (long)bh * SS * DH;
    const bf16_t* Kbh = Kb + (long)bh * SS * DH;
    const bf16_t* Vbh = Vt + (long)bh * DH * SS;

    const int qbase = qt * 128 + w * 32;  // this wave's 32 q rows (2 strips)
    bf16x8 qf[2][2];
#pragma unroll
    for (int s = 0; s < 2; ++s) {
        const long qrow = qbase + 16 * s + l15;
        qf[s][0] = *(const bf16x8*)(Qbh + qrow * DH + l4 * 8);
        qf[s][1] = *(const bf16x8*)(Qbh + qrow * DH + 32 + l4 * 8);
    }
    // drain qf loads: vmcnt state is exactly 0 entering the pipeline loop
    asm volatile("s_waitcnt vmcnt(0)" ::: "memory");
    __builtin_amdgcn_sched_barrier(0);

    const f32x4 vz = {0.f, 0.f, 0.f, 0.f};
    f32x4 oacc[2][4];
#pragma unroll
    for (int s = 0; s < 2; ++s)
#pragma unroll
        for (int j = 0; j < 4; ++j) oacc[s][j] = vz;
    float l_sum[2] = {0.f, 0.f};

    int srow[2], scc[2];
#pragma unroll
    for (int i = 0; i < 2; ++i) {
        const int L = i * 256 + w * 64 + lane;
        srow[i] = L >> 3;
        scc[i]  = (L & 7) ^ (srow[i] & 7);
    }

    const float SC = 0.125f * 1.4426950408889634f;
    const float BI = -8.0f  * 1.4426950408889634f;
    const int NT = SS / 64;

    // stage tile kt2 into buffer b (4 global_load_lds per wave)
    auto stage = [&](int b, int kt2) {
        const bf16_t* Ksrc = Kbh + (long)kt2 * 64 * DH;
#pragma unroll
        for (int i = 0; i < 2; ++i) {
            const int cb = i * 256 + w * 64;
            gload_lds16(Ksrc + srow[i] * 64 + scc[i] * 8, Ks + b * 4096 + cb * 8);
            gload_lds16(Vbh + (long)srow[i] * SS + kt2 * 64 + scc[i] * 8, Vs + b * 4096 + cb * 8);
        }
    };

    stage(0, 0);   // prologue

    for (int kt = 0; kt < NT; ++kt) {
        const int cur = kt & 1;
        if (kt + 1 < NT) {
            stage(cur ^ 1, kt + 1);
            __builtin_amdgcn_sched_barrier(0);
            asm volatile("s_waitcnt vmcnt(4)" ::: "memory");  // cur tile landed; next in flight
        } else {
            asm volatile("s_waitcnt vmcnt(0)" ::: "memory");
        }
        __builtin_amdgcn_sched_barrier(0);
        __builtin_amdgcn_s_barrier();     // all waves' cur-tile loads landed
        __builtin_amdgcn_sched_barrier(0);

        const bf16_t* Ksb = Ks + cur * 4096;
        const bf16_t* Vsb = Vs + cur * 4096;

        // S^T = K Q^T for both strips; kf shared across strips
        f32x4 sacc[2][4];
#pragma unroll
        for (int s = 0; s < 2; ++s)
#pragma unroll
            for (int j = 0; j < 4; ++j) sacc[s][j] = vz;
#pragma unroll
        for (int j = 0; j < 4; ++j) {
            const int rk = (j * 16 + l15) * 64;
            const bf16x8 kf0 = *(const bf16x8*)(Ksb + rk + ((l4 ^ xr) * 8));
            const bf16x8 kf1 = *(const bf16x8*)(Ksb + rk + (((4 + l4) ^ xr) * 8));
#pragma unroll
            for (int s = 0; s < 2; ++s) {
                sacc[s][j] = __builtin_amdgcn_mfma_f32_16x16x32_bf16(kf0, qf[s][0], sacc[s][j], 0, 0, 0);
                sacc[s][j] = __builtin_amdgcn_mfma_f32_16x16x32_bf16(kf1, qf[s][1], sacc[s][j], 0, 0, 0);
            }
        }

        // p = exp2(s*SC + BI), kept in registers as K=16 A-fragments
        short4v pf[2][4];
#pragma unroll
        for (int s = 0; s < 2; ++s) {
#pragma unroll
            for (int j = 0; j < 4; ++j) {
                const float p0 = EXP2F(fmaf(sacc[s][j][0], SC, BI));
                const float p1 = EXP2F(fmaf(sacc[s][j][1], SC, BI));
                const float p2 = EXP2F(fmaf(sacc[s][j][2], SC, BI));
                const float p3 = EXP2F(fmaf(sacc[s][j][3], SC, BI));
                l_sum[s] += (p0 + p1) + (p2 + p3);
                union { bf16x4 h; short4v sv; } cv;
                cv.h.x = (bf16_t)p0; cv.h.y = (bf16_t)p1;
                cv.h.z = (bf16_t)p2; cv.h.w = (bf16_t)p3;
                pf[s][j] = cv.sv;
            }
        }

        // O += P V : dj = d-block, kb = key quad block; vfr shared across strips
#pragma unroll
        for (int dj = 0; dj < 4; ++dj) {
            const bf16_t* vb = Vsb + (dj * 16 + l15) * 64 + (l4 & 1) * 4;
#pragma unroll
            for (int kb = 0; kb < 4; ++kb) {
                const int slot = (kb * 2 + (l4 >> 1)) ^ xr;
                const short4v vfr = *(const short4v*)(vb + slot * 8);
                oacc[0][dj] = mfma16(pf[0][kb], vfr, oacc[0][dj]);
                oacc[1][dj] = mfma16(pf[1][kb], vfr, oacc[1][dj]);
            }
        }

        __builtin_amdgcn_sched_barrier(0);
        __builtin_amdgcn_s_barrier();     // cur buffer free for next-next staging
    }

    const int b = bh >> 4, h = bh & 15;
#pragma unroll
    for (int s = 0; s < 2; ++s) {
        float lt = l_sum[s];
        lt += __shfl_xor(lt, 16);
        lt += __shfl_xor(lt, 32);
        const float inv = 1.0f / lt;
        float invr[4];
#pragma unroll
        for (int r = 0; r < 4; ++r)
            invr[r] = __shfl(inv, l4 * 4 + r);   // lane l4*4+r holds inv for q'=l4*4+r
#pragma unroll
        for (int j = 0; j < 4; ++j) {
#pragma unroll
            for (int r = 0; r < 4; ++r) {
                const int row = qbase + 16 * s + l4 * 4 + r;
                const float v = oacc[s][j][r] * invr[r];
                Ob[((long)(b * SS + row)) * DD + h * DH + j * 16 + l15] = (bf16_t)v;
            }
        }
    }
}

// ---------------------------------------------------------------- launch
extern "C" void kernel_launch(void* const* d_in, const int* in_sizes, int n_in,
                              void* d_out, int out_size, void* d_ws, size_t ws_size,
                              hipStream_t stream)
{
    const float* queries = (const float*)d_in[0];
    const float* Wq = (const float*)d_in[1];
    const float* bq = (const float*)d_in[2];
    const float* Wk = (const float*)d_in[3];
    const float* bk = (const float*)d_in[4];
    const float* Wv = (const float*)d_in[5];
    const float* bv = (const float*)d_in[6];
    const float* Wo = (const float*)d_in[7];
    const float* bo = (const float*)d_in[8];

    char* ws = (char*)d_ws;
    size_t off = 0;
    auto alloc = [&](size_t bytes) { size_t o = off; off += (bytes + 255) & ~(size_t)255; return o; };
    bf16_t* Xb   = (bf16_t*)(ws + alloc(8192u * 1024u * 2u));       // 16 MB
    bf16_t* Wqkv = (bf16_t*)(ws + alloc(3072u * 1024u * 2u));       // 6 MB
    bf16_t* Wob  = (bf16_t*)(ws + alloc(1024u * 1024u * 2u));       // 2 MB
    float*  bqkv = (float*) (ws + alloc(3072u * 4u));
    float2* tab  = (float2*)(ws + alloc(2048u * 512u * 8u));        // 8 MB
    bf16_t* Qb   = (bf16_t*)(ws + alloc(64u * 2048u * 64u * 2u));   // 16 MB
    bf16_t* Kb   = (bf16_t*)(ws + alloc(64u * 2048u * 64u * 2u));   // 16 MB
    bf16_t* Vt   = (bf16_t*)(ws + alloc(64u * 64u * 2048u * 2u));   // 16 MB
    bf16_t* Ob   = Xb;  // alias: Xb is dead after GEMM1

    prep_kernel<<<16396, 256, 0, stream>>>(queries, Wq, Wk, Wv, Wo, bq, bk, bv,
                                           Xb, Wqkv, Wob, bqkv, tab);

    gemm_qkv_rope<<<dim3(64, 24), 256, 0, stream>>>(Xb, Wqkv, bqkv, tab, Qb, Kb, Vt);
    attn_kernel<<<dim3(64, 16), 256, 0, stream>>>(Qb, Kb, Vt, Ob);
    gemm_bt<0><<<dim3(64, 8), 256, 0, stream>>>(Ob, Wob, bo, d_out, 8192, 1024, 1024);
}

// Round 3
// 287.364 us; speedup vs baseline: 1.0968x; 1.0594x over previous
//
#include <hip/hip_runtime.h>
#include <stdint.h>

typedef __bf16 bf16_t;
typedef __bf16 bf16x4 __attribute__((ext_vector_type(4)));
typedef __bf16 bf16x8 __attribute__((ext_vector_type(8)));
typedef float  f32x4  __attribute__((ext_vector_type(4)));

#define BB   4
#define SS   2048
#define DD   1024
#define HH   16
#define DH   64

#if __has_builtin(__builtin_amdgcn_exp2f)
#define EXP2F(x) __builtin_amdgcn_exp2f(x)
#else
#define EXP2F(x) __expf((x) * 0.6931471805599453f)
#endif

// Q pre-scale: 0.125 * log2(e). Folded into Qb at the GEMM1 epilogue (f32
// multiply BEFORE bf16 round -> zero precision cost, bf16 rounding is
// scale-invariant). Softmax is invariant to a constant factor on p, so the
// old -8 bias is dropped entirely; attn inner loop does p = exp2(s) raw.
#define QSC 0.18033688011112042f

// ---------------------------------------------------------------- helpers
__device__ __forceinline__ void gload_lds16(const void* g, void* l) {
    // dest LDS addr = wave-uniform base + lane*16 (measured m104/m108)
    __builtin_amdgcn_global_load_lds(
        (__attribute__((address_space(1))) void*)(uintptr_t)g,
        (__attribute__((address_space(3))) void*)(uint32_t)(uintptr_t)l,
        16, 0, 0);
}

// ---------------------------------------------------------------- fused prep
// one launch: X fp32->bf16 (8192 blocks), 4 weights fp32->bf16 (4096),
// rope cos/sin table (4096), bias pack (12). grid = 16396.
__global__ __launch_bounds__(256) void prep_kernel(
        const float* __restrict__ queries,
        const float* __restrict__ Wq, const float* __restrict__ Wk,
        const float* __restrict__ Wv, const float* __restrict__ Wo,
        const float* __restrict__ bq, const float* __restrict__ bk,
        const float* __restrict__ bv,
        bf16_t* __restrict__ Xb, bf16_t* __restrict__ Wqkv,
        bf16_t* __restrict__ Wob, float* __restrict__ bqkv,
        float2* __restrict__ tab)
{
    const int bid = blockIdx.x, t = threadIdx.x;
    if (bid < 8192) {                       // X convert: 2097152 float4
        const int i = bid * 256 + t;
        float4 v = ((const float4*)queries)[i];
        bf16x4 o;
        o.x = (bf16_t)v.x; o.y = (bf16_t)v.y; o.z = (bf16_t)v.z; o.w = (bf16_t)v.w;
        ((bf16x4*)Xb)[i] = o;
    } else if (bid < 12288) {               // weights: 1048576 float4
        const int i = (bid - 8192) * 256 + t;
        const int which = i >> 18, p = i & 262143;
        const float* src = (which == 0) ? Wq : (which == 1) ? Wk : (which == 2) ? Wv : Wo;
        bf16_t* dst = (which < 3) ? (Wqkv + (long)which * 1048576) : Wob;
        float4 v = ((const float4*)src)[p];
        bf16x4 o;
        o.x = (bf16_t)v.x; o.y = (bf16_t)v.y; o.z = (bf16_t)v.z; o.w = (bf16_t)v.w;
        ((bf16x4*)dst)[p] = o;
    } else if (bid < 16384) {               // rope table: 2048*512 entries
        const int i = (bid - 12288) * 256 + t;
        const int s = i >> 9, pr = i & 511;
        // 10000^(-2pr/1024) = exp2(-2pr * log2(10000)/1024); exp2f is HW-fast
        float inv = exp2f(-(float)(2 * pr) * 0.012976281620653759f);
        float c, sn;
        sincosf((float)s * inv, &sn, &c);
        tab[i] = make_float2(c, sn);
    } else {                                // bias pack: 3072
        const int i = (bid - 16384) * 256 + t;
        if (i < 3072)
            bqkv[i] = (i < 1024) ? bq[i] : ((i < 2048) ? bk[i - 1024] : bv[i - 2048]);
    }
}

// ---------------------------------------------------------------- fused QKV GEMM + bias + RoPE + V-transpose
// C = X @ Wqkv^T + bqkv. Q/K cols -> rope -> Qb/Kb (bh, s, d); V cols ->
// written TRANSPOSED directly to Vt (bh, d, s). Q additionally scaled by
// QSC (softmax scale folded out of the attn inner loop).
__global__ __launch_bounds__(256, 3) void gemm_qkv_rope(
        const bf16_t* __restrict__ A, const bf16_t* __restrict__ Bm,
        const float* __restrict__ bias, const float2* __restrict__ tab,
        bf16_t* __restrict__ Qb, bf16_t* __restrict__ Kb, bf16_t* __restrict__ Vt)
{
    __shared__ __attribute__((aligned(16))) bf16_t As[128 * 32];
    __shared__ __attribute__((aligned(16))) bf16_t Bs[128 * 32];
    const int t = threadIdx.x;
    const int lane = t & 63, w = t >> 6;
    const int wm = w >> 1, wn = w & 1;
    const int l15 = lane & 15, l4 = lane >> 4;
    const int xg = l15 & 3;                  // read-side swizzle (= row&3)
    const long rowA0 = (long)blockIdx.x * 128;
    const long rowB0 = (long)blockIdx.y * 128;
    const int K = 1024;

    const f32x4 vz = {0.f, 0.f, 0.f, 0.f};
    f32x4 acc[4][4];
#pragma unroll
    for (int i = 0; i < 4; ++i)
#pragma unroll
        for (int j = 0; j < 4; ++j) acc[i][j] = vz;

    for (int kk = 0; kk < K; kk += 32) {
        __syncthreads();
#pragma unroll
        for (int i = 0; i < 2; ++i) {
            const int cb = i * 256 + w * 64;
            const int c  = cb + lane;
            const int r  = c >> 2;
            const int ko = ((c & 3) ^ (r & 3)) << 3;   // swizzled src chunk
            gload_lds16(A  + (rowA0 + r) * K + kk + ko, As + cb * 8);
            gload_lds16(Bm + (rowB0 + r) * K + kk + ko, Bs + cb * 8);
        }
        __syncthreads();
        bf16x8 af[4], bfr[4];
#pragma unroll
        for (int i = 0; i < 4; ++i)
            af[i] = *(const bf16x8*)(As + (wm * 64 + i * 16 + l15) * 32 + ((l4 ^ xg) * 8));
#pragma unroll
        for (int j = 0; j < 4; ++j)
            bfr[j] = *(const bf16x8*)(Bs + (wn * 64 + j * 16 + l15) * 32 + ((l4 ^ xg) * 8));
#pragma unroll
        for (int i = 0; i < 4; ++i)
#pragma unroll
            for (int j = 0; j < 4; ++j)
                acc[i][j] = __builtin_amdgcn_mfma_f32_16x16x32_bf16(af[i], bfr[j], acc[i][j], 0, 0, 0);
    }

    const long crow0 = rowA0 + wm * 64;
    const int  ccol0 = (int)rowB0 + wn * 64;     // global col in [0,3072), multiple of 64
    const int  part  = blockIdx.y >> 3;          // 0=Q, 1=K, 2=V
    const int  b     = (int)(crow0 >> 11);
    const int  s0    = (int)(crow0 & 2047);      // 64 rows stay in one batch

    if (part == 2) {
        const int h = (ccol0 - 2048) >> 6;       // wave-constant head
#pragma unroll
        for (int j = 0; j < 4; ++j) {
            const int d = j * 16 + l15;
            const float bb = bias[ccol0 + j * 16 + l15];
            bf16_t* dstc = Vt + ((long)(b * HH + h) * DH + d) * SS + s0;
#pragma unroll
            for (int i = 0; i < 4; ++i) {
                bf16x4 pk;
                pk.x = (bf16_t)(acc[i][j][0] + bb);
                pk.y = (bf16_t)(acc[i][j][1] + bb);
                pk.z = (bf16_t)(acc[i][j][2] + bb);
                pk.w = (bf16_t)(acc[i][j][3] + bb);
                *(bf16x4*)(dstc + i * 16 + l4 * 4) = pk;
            }
        }
    } else {
        bf16_t* dst0 = part ? Kb : Qb;
        const float osc = part ? 1.0f : QSC;     // fold softmax scale into Q
        const int h = (ccol0 & 1023) >> 6;       // this wave's 64-col strip = one head
        const int even = !(l15 & 1);
#pragma unroll
        for (int i = 0; i < 4; ++i) {
#pragma unroll
            for (int j = 0; j < 4; ++j) {
                const int col = ccol0 + j * 16 + l15;
                const float bb = bias[col];
                const int dd = j * 16 + l15;
                const float2* trow = tab + (col >> 1 & 511);
#pragma unroll
                for (int r = 0; r < 4; ++r) {
                    const int s = s0 + i * 16 + l4 * 4 + r;
                    const float val = acc[i][j][r] + bb;
                    const float par = __shfl_xor(val, 1);
                    const float2 cs = trow[s * 512];
                    const float out = even ? (val * cs.x - par * cs.y)
                                           : fmaf(val, cs.x, par * cs.y);
                    // pair-store: even lane writes {out_even, out_odd} as b32
                    const float op = __shfl_xor(out, 1);
                    if (even) {
                        union { bf16_t hh[2]; unsigned int u; } cv;
                        cv.hh[0] = (bf16_t)(out * osc); cv.hh[1] = (bf16_t)(op * osc);
                        *(unsigned int*)(dst0 + ((long)((b * HH + h) * SS + s)) * DH + dd) = cv.u;
                    }
                }
            }
        }
    }
}

// ---------------------------------------------------------------- NT GEMM (output projection)
template <int OUT_BF16>
__global__ __launch_bounds__(256, 3) void gemm_bt(
        const bf16_t* __restrict__ A, const bf16_t* __restrict__ Bm,
        const float* __restrict__ bias, void* __restrict__ Cout,
        int M, int N, int K)
{
    __shared__ __attribute__((aligned(16))) bf16_t As[128 * 32];
    __shared__ __attribute__((aligned(16))) bf16_t Bs[128 * 32];
    const int t = threadIdx.x;
    const int lane = t & 63, w = t >> 6;
    const int wm = w >> 1, wn = w & 1;
    const int l15 = lane & 15, l4 = lane >> 4;
    const int xg = l15 & 3;
    const long rowA0 = (long)blockIdx.x * 128;
    const long rowB0 = (long)blockIdx.y * 128;

    const f32x4 vz = {0.f, 0.f, 0.f, 0.f};
    f32x4 acc[4][4];
#pragma unroll
    for (int i = 0; i < 4; ++i)
#pragma unroll
        for (int j = 0; j < 4; ++j) acc[i][j] = vz;

    for (int kk = 0; kk < K; kk += 32) {
        __syncthreads();
#pragma unroll
        for (int i = 0; i < 2; ++i) {
            const int cb = i * 256 + w * 64;
            const int c  = cb + lane;
            const int r  = c >> 2;
            const int ko = ((c & 3) ^ (r & 3)) << 3;   // swizzled src chunk
            gload_lds16(A  + (rowA0 + r) * K + kk + ko, As + cb * 8);
            gload_lds16(Bm + (rowB0 + r) * K + kk + ko, Bs + cb * 8);
        }
        __syncthreads();
        bf16x8 af[4], bfr[4];
#pragma unroll
        for (int i = 0; i < 4; ++i)
            af[i] = *(const bf16x8*)(As + (wm * 64 + i * 16 + l15) * 32 + ((l4 ^ xg) * 8));
#pragma unroll
        for (int j = 0; j < 4; ++j)
            bfr[j] = *(const bf16x8*)(Bs + (wn * 64 + j * 16 + l15) * 32 + ((l4 ^ xg) * 8));
#pragma unroll
        for (int i = 0; i < 4; ++i)
#pragma unroll
            for (int j = 0; j < 4; ++j)
                acc[i][j] = __builtin_amdgcn_mfma_f32_16x16x32_bf16(af[i], bfr[j], acc[i][j], 0, 0, 0);
    }

    const long crow0 = rowA0 + wm * 64;
    const int  ccol0 = (int)rowB0 + wn * 64;
#pragma unroll
    for (int i = 0; i < 4; ++i) {
#pragma unroll
        for (int j = 0; j < 4; ++j) {
            const int col = ccol0 + j * 16 + l15;
            const float bb = bias[col];
#pragma unroll
            for (int r = 0; r < 4; ++r) {
                const long row = crow0 + i * 16 + l4 * 4 + r;
                const float v = acc[i][j][r] + bb;
                if (OUT_BF16) ((bf16_t*)Cout)[row * N + col] = (bf16_t)v;
                else          ((float*)Cout)[row * N + col]  = v;
            }
        }
    }
}

// ---------------------------------------------------------------- flash attention
// R11 = R8 structure EXACTLY (best measured: 98.5 us — single-buffer K/V,
// Ps in LDS, 128-row q-tile, 2 strips/wave, two __syncthreads per kt,
// compiler-scheduled; R10's dbuf+sched_barrier pinning and in-register-P
// both measured WORSE) + VALU diet:
//  - Q pre-scaled by QSC in GEMM1, bias dropped (softmax scale-invariant):
//    p = exp2(sacc) raw. -32 v_fma per wave-iter.
//  - l_sum via ones-column MFMA on the pf fragments (P·1 = row sums), on the
//    under-used MFMA pipe: -32 VALU adds per wave-iter. Its D-layout row
//    (l4*4+r) matches oacc's exactly, so the epilogue shuffle-reduce chain
//    becomes invr[r] = 1/lacc[s][r]. Denominator uses the same bf16-rounded
//    p as the numerator (consistency bonus).
//  - bh-major grid kept (XCD pinning, FETCH 139->33 MB measured, dur-neutral).
__global__ __launch_bounds__(256, 4) void attn_kernel(const bf16_t* __restrict__ Qb,
                                                      const bf16_t* __restrict__ Kb,
                                                      const bf16_t* __restrict__ Vt,
                                                      bf16_t* __restrict__ Ob)
{
    __shared__ __attribute__((aligned(16))) bf16_t Ks[64 * 64];   // [key][d], swizzled
    __shared__ __attribute__((aligned(16))) bf16_t Vs[64 * 64];   // [d][key], swizzled
    __shared__ __attribute__((aligned(16))) bf16_t Ps[128 * 72];  // [q][key], pitch 72
    const int t = threadIdx.x, lane = t & 63, w = t >> 6;
    const int l15 = lane & 15, l4 = lane >> 4;
    const int xr = l15 & 7;               // read-side swizzle pattern (= row&7)
    const int bh = blockIdx.x, qt = blockIdx.y;
    const bf16_t* Qbh = Qb + (long)bh * SS * DH;
    const bf16_t* Kbh = Kb + (long)bh * SS * DH;
    const bf16_t* Vbh = Vt + (long)bh * DH * SS;

    const int qbase = qt * 128 + w * 32;
    bf16x8 qf[2][2];
#pragma unroll
    for (int s = 0; s < 2; ++s) {
        const long qrow = qbase + 16 * s + l15;
        qf[s][0] = *(const bf16x8*)(Qbh + qrow * DH + l4 * 8);
        qf[s][1] = *(const bf16x8*)(Qbh + qrow * DH + 32 + l4 * 8);
    }

    bf16x8 ones;
#pragma unroll
    for (int e = 0; e < 8; ++e) ones[e] = (bf16_t)1.0f;

    const f32x4 vz = {0.f, 0.f, 0.f, 0.f};
    f32x4 oacc[2][4];
    f32x4 lacc[2];
#pragma unroll
    for (int s = 0; s < 2; ++s) {
        lacc[s] = vz;
#pragma unroll
        for (int j = 0; j < 4; ++j) oacc[s][j] = vz;
    }

    int srow[2], scc[2];
#pragma unroll
    for (int i = 0; i < 2; ++i) {
        const int L = i * 256 + w * 64 + lane;
        srow[i] = L >> 3;
        scc[i]  = (L & 7) ^ (srow[i] & 7);
    }

    for (int kt = 0; kt < SS / 64; ++kt) {
        __syncthreads();
        const bf16_t* Ksrc = Kbh + (long)kt * 64 * DH;
#pragma unroll
        for (int i = 0; i < 2; ++i) {
            const int cb = i * 256 + w * 64;
            gload_lds16(Ksrc + srow[i] * 64 + scc[i] * 8, Ks + cb * 8);
            gload_lds16(Vbh + (long)srow[i] * SS + kt * 64 + scc[i] * 8, Vs + cb * 8);
        }
        __syncthreads();

        // S^T = K Q^T for both strips; kf shared across strips
        f32x4 sacc[2][4];
#pragma unroll
        for (int s = 0; s < 2; ++s)
#pragma unroll
            for (int j = 0; j < 4; ++j) sacc[s][j] = vz;
#pragma unroll
        for (int j = 0; j < 4; ++j) {
            const int rk = (j * 16 + l15) * 64;
            const bf16x8 kf0 = *(const bf16x8*)(Ks + rk + ((l4 ^ xr) * 8));
            const bf16x8 kf1 = *(const bf16x8*)(Ks + rk + (((4 + l4) ^ xr) * 8));
#pragma unroll
            for (int s = 0; s < 2; ++s) {
                sacc[s][j] = __builtin_amdgcn_mfma_f32_16x16x32_bf16(kf0, qf[s][0], sacc[s][j], 0, 0, 0);
                sacc[s][j] = __builtin_amdgcn_mfma_f32_16x16x32_bf16(kf1, qf[s][1], sacc[s][j], 0, 0, 0);
            }
        }

        // p = exp2(s) (scale folded into Q, bias dropped — softmax invariant)
#pragma unroll
        for (int s = 0; s < 2; ++s) {
#pragma unroll
            for (int j = 0; j < 4; ++j) {
                const float p0 = EXP2F(sacc[s][j][0]);
                const float p1 = EXP2F(sacc[s][j][1]);
                const float p2 = EXP2F(sacc[s][j][2]);
                const float p3 = EXP2F(sacc[s][j][3]);
                bf16x4 pk;
                pk.x = (bf16_t)p0; pk.y = (bf16_t)p1; pk.z = (bf16_t)p2; pk.w = (bf16_t)p3;
                *(bf16x4*)(Ps + (w * 32 + 16 * s + l15) * 72 + j * 16 + l4 * 4) = pk;
            }
        }
        // no __syncthreads(): Ps rows [w*32, w*32+32) are wave-local;
        // in-wave DS ops complete in order.

        bf16x8 pf[2][2];
#pragma unroll
        for (int s = 0; s < 2; ++s) {
            pf[s][0] = *(const bf16x8*)(Ps + (w * 32 + 16 * s + l15) * 72 + l4 * 8);
            pf[s][1] = *(const bf16x8*)(Ps + (w * 32 + 16 * s + l15) * 72 + 32 + l4 * 8);
            // row sums on the MFMA pipe: lacc[s][r] = sum_k P[q=l4*4+r][k]
            lacc[s] = __builtin_amdgcn_mfma_f32_16x16x32_bf16(pf[s][0], ones, lacc[s], 0, 0, 0);
            lacc[s] = __builtin_amdgcn_mfma_f32_16x16x32_bf16(pf[s][1], ones, lacc[s], 0, 0, 0);
        }
#pragma unroll
        for (int j = 0; j < 4; ++j) {
            const int rv = (j * 16 + l15) * 64;
            const bf16x8 vf0 = *(const bf16x8*)(Vs + rv + ((l4 ^ xr) * 8));
            const bf16x8 vf1 = *(const bf16x8*)(Vs + rv + (((4 + l4) ^ xr) * 8));
#pragma unroll
            for (int s = 0; s < 2; ++s) {
                oacc[s][j] = __builtin_amdgcn_mfma_f32_16x16x32_bf16(pf[s][0], vf0, oacc[s][j], 0, 0, 0);
                oacc[s][j] = __builtin_amdgcn_mfma_f32_16x16x32_bf16(pf[s][1], vf1, oacc[s][j], 0, 0, 0);
            }
        }
    }

    const int b = bh >> 4, h = bh & 15;
#pragma unroll
    for (int s = 0; s < 2; ++s) {
        float invr[4];
#pragma unroll
        for (int r = 0; r < 4; ++r)
            invr[r] = 1.0f / lacc[s][r];      // layout matches oacc rows directly
#pragma unroll
        for (int j = 0; j < 4; ++j) {
#pragma unroll
            for (int r = 0; r < 4; ++r) {
                const int row = qbase + 16 * s + l4 * 4 + r;
                const float v = oacc[s][j][r] * invr[r];
                Ob[((long)(b * SS + row)) * DD + h * DH + j * 16 + l15] = (bf16_t)v;
            }
        }
    }
}

// ---------------------------------------------------------------- launch
extern "C" void kernel_launch(void* const* d_in, const int* in_sizes, int n_in,
                              void* d_out, int out_size, void* d_ws, size_t ws_size,
                              hipStream_t stream)
{
    const float* queries = (const float*)d_in[0];
    const float* Wq = (const float*)d_in[1];
    const float* bq = (const float*)d_in[2];
    const float* Wk = (const float*)d_in[3];
    const float* bk = (const float*)d_in[4];
    const float* Wv = (const float*)d_in[5];
    const float* bv = (const float*)d_in[6];
    const float* Wo = (const float*)d_in[7];
    const float* bo = (const float*)d_in[8];

    char* ws = (char*)d_ws;
    size_t off = 0;
    auto alloc = [&](size_t bytes) { size_t o = off; off += (bytes + 255) & ~(size_t)255; return o; };
    bf16_t* Xb   = (bf16_t*)(ws + alloc(8192u * 1024u * 2u));       // 16 MB
    bf16_t* Wqkv = (bf16_t*)(ws + alloc(3072u * 1024u * 2u));       // 6 MB
    bf16_t* Wob  = (bf16_t*)(ws + alloc(1024u * 1024u * 2u));       // 2 MB
    float*  bqkv = (float*) (ws + alloc(3072u * 4u));
    float2* tab  = (float2*)(ws + alloc(2048u * 512u * 8u));        // 8 MB
    bf16_t* Qb   = (bf16_t*)(ws + alloc(64u * 2048u * 64u * 2u));   // 16 MB
    bf16_t* Kb   = (bf16_t*)(ws + alloc(64u * 2048u * 64u * 2u));   // 16 MB
    bf16_t* Vt   = (bf16_t*)(ws + alloc(64u * 64u * 2048u * 2u));   // 16 MB
    bf16_t* Ob   = Xb;  // alias: Xb is dead after GEMM1

    prep_kernel<<<16396, 256, 0, stream>>>(queries, Wq, Wk, Wv, Wo, bq, bk, bv,
                                           Xb, Wqkv, Wob, bqkv, tab);

    gemm_qkv_rope<<<dim3(64, 24), 256, 0, stream>>>(Xb, Wqkv, bqkv, tab, Qb, Kb, Vt);
    attn_kernel<<<dim3(64, 16), 256, 0, stream>>>(Qb, Kb, Vt, Ob);
    gemm_bt<0><<<dim3(64, 8), 256, 0, stream>>>(Ob, Wob, bo, d_out, 8192, 1024, 1024);
}